// Round 1
// baseline (24.096 us; speedup 1.0000x reference)
//
#include <hip/hip_runtime.h>

#define F 8
#define L 16
#define XN 8
#define YN 4

// out layout: [L*N] (norm.T) followed by [YN*N] (out.T)
__global__ __launch_bounds__(256) void eafnn_kernel(
    const float* __restrict__ inp,
    const float* __restrict__ x,
    const float* __restrict__ c,
    const float* __restrict__ b,
    const float* __restrict__ w,
    float* __restrict__ out,
    int n_total)
{
    __shared__ __attribute__((aligned(16))) float s_c[F * L];
    __shared__ __attribute__((aligned(16))) float s_k[F * L];   // -log2(e)/(2 b^2)
    __shared__ __attribute__((aligned(16))) float s_w[L * XN * YN];

    const int tid = threadIdx.x;
    if (tid < F * L) {
        float bb = b[tid];
        s_c[tid] = c[tid];
        s_k[tid] = -1.4426950408889634f / (2.0f * bb * bb);
    }
    for (int i = tid; i < L * XN * YN; i += 256) s_w[i] = w[i];
    __syncthreads();

    const int n = blockIdx.x * 256 + tid;
    if (n >= n_total) return;

    // ---- membership accumulation in log2 domain ----
    const float4* ip = (const float4*)(inp + (size_t)n * F);
    float4 a0 = ip[0], a1 = ip[1];
    float fi[F] = {a0.x, a0.y, a0.z, a0.w, a1.x, a1.y, a1.z, a1.w};

    float s[L];
#pragma unroll
    for (int l = 0; l < L; ++l) s[l] = 0.0f;

#pragma unroll
    for (int f = 0; f < F; ++f) {
        float v = fi[f];
#pragma unroll
        for (int lq = 0; lq < L / 4; ++lq) {
            float4 cq = *(const float4*)&s_c[f * L + lq * 4];
            float4 kq = *(const float4*)&s_k[f * L + lq * 4];
            float d0 = v - cq.x, d1 = v - cq.y, d2 = v - cq.z, d3 = v - cq.w;
            s[lq * 4 + 0] = fmaf(d0 * d0, kq.x, s[lq * 4 + 0]);
            s[lq * 4 + 1] = fmaf(d1 * d1, kq.y, s[lq * 4 + 1]);
            s[lq * 4 + 2] = fmaf(d2 * d2, kq.z, s[lq * 4 + 2]);
            s[lq * 4 + 3] = fmaf(d3 * d3, kq.w, s[lq * 4 + 3]);
        }
    }

    // ---- firing + normalization (single exp2 per rule) ----
    float firing[L];
    float tot = 0.0f;
#pragma unroll
    for (int l = 0; l < L; ++l) {
        firing[l] = __builtin_amdgcn_exp2f(s[l]) + 0.001f;
        tot += firing[l];
    }
    float inv = 1.0f / tot;

    float norm[L];
#pragma unroll
    for (int l = 0; l < L; ++l) {
        norm[l] = firing[l] * inv;
        out[(size_t)l * n_total + n] = norm[l];   // norm.T [L][N], coalesced per l
    }

    // ---- linear consequents: out[y] = sum_x x[n,x] * (sum_l norm[l] w[l,x,y]) ----
    const float4* xp = (const float4*)(x + (size_t)n * XN);
    float4 x0 = xp[0], x1 = xp[1];
    float xv[XN] = {x0.x, x0.y, x0.z, x0.w, x1.x, x1.y, x1.z, x1.w};

    float weff[XN * YN];
#pragma unroll
    for (int i = 0; i < XN * YN; ++i) weff[i] = 0.0f;

#pragma unroll
    for (int l = 0; l < L; ++l) {
        float nl = norm[l];
#pragma unroll
        for (int i = 0; i < XN * YN; i += 4) {
            float4 wq = *(const float4*)&s_w[l * XN * YN + i];
            weff[i + 0] = fmaf(nl, wq.x, weff[i + 0]);
            weff[i + 1] = fmaf(nl, wq.y, weff[i + 1]);
            weff[i + 2] = fmaf(nl, wq.z, weff[i + 2]);
            weff[i + 3] = fmaf(nl, wq.w, weff[i + 3]);
        }
    }

    float acc[YN] = {0.f, 0.f, 0.f, 0.f};
#pragma unroll
    for (int xx = 0; xx < XN; ++xx) {
#pragma unroll
        for (int y = 0; y < YN; ++y)
            acc[y] = fmaf(xv[xx], weff[xx * YN + y], acc[y]);
    }

    float* out_y = out + (size_t)L * n_total;
#pragma unroll
    for (int y = 0; y < YN; ++y)
        out_y[(size_t)y * n_total + n] = acc[y];  // out.T [YN][N], coalesced per y
}

extern "C" void kernel_launch(void* const* d_in, const int* in_sizes, int n_in,
                              void* d_out, int out_size, void* d_ws, size_t ws_size,
                              hipStream_t stream) {
    const float* inp = (const float*)d_in[0];
    const float* x   = (const float*)d_in[1];
    const float* c   = (const float*)d_in[2];
    const float* b   = (const float*)d_in[3];
    const float* w   = (const float*)d_in[4];
    float* out = (float*)d_out;

    int n_total = in_sizes[0] / F;   // 500000
    int grid = (n_total + 255) / 256;
    eafnn_kernel<<<grid, 256, 0, stream>>>(inp, x, c, b, w, out, n_total);
}